// Round 8
// baseline (284.470 us; speedup 1.0000x reference)
//
#include <hip/hip_runtime.h>

#define N_NODES 100000
#define N_EDGES 3200000
#define RPB 128
#define NB ((N_NODES + RPB - 1) / RPB)       // 782 buckets

typedef unsigned short ushort_t;
typedef unsigned int uint_t;

__device__ __forceinline__ ushort_t f32_to_bf16_rne(float f) {
    uint_t b = __float_as_uint(f);
    return (ushort_t)((b + 0x7FFFu + ((b >> 16) & 1u)) >> 16);
}
__device__ __forceinline__ float bf16_to_f32(ushort_t u) {
    return __uint_as_float(((uint_t)u) << 16);
}

// ---------------- dense parts ----------------

__global__ void gemm_w12_kernel(const float* __restrict__ W1,
                                const float* __restrict__ W2,
                                float* __restrict__ W12) {
    int idx = blockIdx.x * blockDim.x + threadIdx.x;
    if (idx >= 32 * 128) return;
    int r = idx >> 7;
    int c = idx & 127;
    float acc = 0.f;
#pragma unroll
    for (int k = 0; k < 64; ++k) acc += W1[r * 64 + k] * W2[k * 128 + c];
    W12[idx] = acc;
}

// feat (fp32) -> bf16 table
__global__ void cvt_bf16_kernel(const float* __restrict__ in, ushort_t* __restrict__ ob) {
    int i = blockIdx.x * blockDim.x + threadIdx.x;
    if (i < N_NODES * 32) ob[i] = f32_to_bf16_rne(in[i]);
}

// out[r][jo:jo+4] = sum_k g2[r][k] * W12[k][jo:jo+4]
__global__ void gemm_out_kernel(const float* __restrict__ g2,
                                const float* __restrict__ W12,
                                float* __restrict__ out) {
    int tid = threadIdx.x;
    int jo = (tid & 31) * 4;
    int rl = tid >> 5;
    float4 w[32];
#pragma unroll
    for (int k = 0; k < 32; ++k) w[k] = *(const float4*)&W12[k * 128 + jo];
    for (int r = blockIdx.x * 8 + rl; r < N_NODES; r += gridDim.x * 8) {
        const float4* g4 = (const float4*)(g2 + (size_t)r * 32);
        float4 acc = make_float4(0.f, 0.f, 0.f, 0.f);
#pragma unroll
        for (int q = 0; q < 8; ++q) {
            float4 gv = g4[q];
            int k = q * 4;
            acc.x += gv.x * w[k].x;     acc.y += gv.x * w[k].y;
            acc.z += gv.x * w[k].z;     acc.w += gv.x * w[k].w;
            acc.x += gv.y * w[k + 1].x; acc.y += gv.y * w[k + 1].y;
            acc.z += gv.y * w[k + 1].z; acc.w += gv.y * w[k + 1].w;
            acc.x += gv.z * w[k + 2].x; acc.y += gv.z * w[k + 2].y;
            acc.z += gv.z * w[k + 2].z; acc.w += gv.z * w[k + 2].w;
            acc.x += gv.w * w[k + 3].x; acc.y += gv.w * w[k + 3].y;
            acc.z += gv.w * w[k + 3].z; acc.w += gv.w * w[k + 3].w;
        }
        *(float4*)&out[(size_t)r * 128 + jo] = acc;
    }
}

// ---------------- bucket-level hist + scan ----------------

__global__ void hist_bucket_kernel(const int* __restrict__ row, int* __restrict__ cnt) {
    __shared__ int h[NB];
    for (int t = threadIdx.x; t < NB; t += blockDim.x) h[t] = 0;
    __syncthreads();
    int per = (N_EDGES + gridDim.x - 1) / gridDim.x;
    int s = blockIdx.x * per;
    int e = min(s + per, N_EDGES);
    for (int i = s + threadIdx.x; i < e; i += blockDim.x)
        atomicAdd(&h[row[i] >> 7], 1);
    __syncthreads();
    for (int t = threadIdx.x; t < NB; t += blockDim.x)
        if (h[t]) atomicAdd(&cnt[t], h[t]);
}

__global__ void scan_bucket_kernel(const int* __restrict__ cnt,
                                   int* __restrict__ offs, int* __restrict__ cur_b) {
    __shared__ int s[1024];
    int t = threadIdx.x;
    int v = (t < NB) ? cnt[t] : 0;
    s[t] = v;
    __syncthreads();
    for (int off = 1; off < 1024; off <<= 1) {
        int add = (t >= off) ? s[t - off] : 0;
        __syncthreads();
        s[t] += add;
        __syncthreads();
    }
    if (t < NB) { int x = s[t] - v; offs[t] = x; cur_b[t] = x; }
    if (t == 0) offs[NB] = N_EDGES;
}

// ---------------- hop-1: block-aggregated bucket scatter (1024 threads) ----------------
__global__ void scatter_bucket_kernel(const int* __restrict__ row, const int* __restrict__ col,
                                      const float* __restrict__ val,
                                      int* __restrict__ cur_b, int2* __restrict__ ebuf) {
    __shared__ int h[NB];
    __shared__ int base[NB];
    for (int t = threadIdx.x; t < NB; t += blockDim.x) h[t] = 0;
    __syncthreads();
    int per = (N_EDGES + gridDim.x - 1) / gridDim.x;
    int s = blockIdx.x * per;
    int e = min(s + per, N_EDGES);
    for (int i = s + threadIdx.x; i < e; i += blockDim.x)
        atomicAdd(&h[row[i] >> 7], 1);
    __syncthreads();
    for (int t = threadIdx.x; t < NB; t += blockDim.x) {
        int c = h[t];
        base[t] = c ? atomicAdd(&cur_b[t], c) : 0;
        h[t] = 0;
    }
    __syncthreads();
    for (int i = s + threadIdx.x; i < e; i += blockDim.x) {
        int r = row[i];
        int b = r >> 7;
        int lp = atomicAdd(&h[b], 1);
        ebuf[base[b] + lp] = make_int2((col[i] << 7) | (r & 127), __float_as_int(val[i]));
    }
}

// ---------------- hop-2: per-bucket LDS rowsort (512 threads); writes rs ----------------
__global__ void rowsort_kernel(const int* __restrict__ offs, const int2* __restrict__ ebuf,
                               int2* __restrict__ ep, int* __restrict__ rs) {
    __shared__ int h[RPB];
    __shared__ int loff[RPB];
    __shared__ int curl[RPB];
    int b = blockIdx.x;
    int s = offs[b], e = offs[b + 1];
    int t = threadIdx.x;
    if (t < RPB) h[t] = 0;
    __syncthreads();
    for (int i = s + t; i < e; i += blockDim.x)
        atomicAdd(&h[ebuf[i].x & 127], 1);
    __syncthreads();
    if (t < RPB) loff[t] = h[t];
    __syncthreads();
    for (int off = 1; off < RPB; off <<= 1) {
        int add = (t < RPB && t >= off) ? loff[t - off] : 0;
        __syncthreads();
        if (t < RPB) loff[t] += add;
        __syncthreads();
    }
    if (t < RPB) {
        int excl = loff[t] - h[t];
        curl[t] = excl;
        int r = b * RPB + t;
        if (r < N_NODES) rs[r] = s + excl;
    }
    if (b == 0 && t == 0) rs[N_NODES] = N_EDGES;
    __syncthreads();
    for (int i = s + t; i < e; i += blockDim.x) {
        int2 cv = ebuf[i];
        int rl = cv.x & 127;
        int pos = s + atomicAdd(&curl[rl], 1);
        ep[pos] = make_int2(cv.x >> 7, cv.y);   // {col, valbits}
    }
}

// ---------------- CSR SpMM over bf16 table, 8-deep unrolled ----------------
// x gathered as bf16 (64B rows), fp32 accumulation; OUT_BF16 selects output fmt
template <bool OUT_BF16>
__global__ void spmm_csr_kernel(const int* __restrict__ rs,
                                const int2* __restrict__ ep,
                                const ushort_t* __restrict__ xb,
                                void* __restrict__ outv) {
    int gid = blockIdx.x * blockDim.x + threadIdx.x;
    int r = gid >> 6;
    if (r >= N_NODES) return;
    int lane = threadIdx.x & 63;
    int j = lane & 31;
    int half = lane >> 5;
    int s = rs[r], e = rs[r + 1];
    float a0 = 0.f, a1 = 0.f, a2 = 0.f, a3 = 0.f;
    int p = s + half;
    for (; p + 14 < e; p += 16) {
        int2 c0 = ep[p];
        int2 c1 = ep[p + 2];
        int2 c2 = ep[p + 4];
        int2 c3 = ep[p + 6];
        int2 c4 = ep[p + 8];
        int2 c5 = ep[p + 10];
        int2 c6 = ep[p + 12];
        int2 c7 = ep[p + 14];
        ushort_t u0 = xb[c0.x * 32 + j];
        ushort_t u1 = xb[c1.x * 32 + j];
        ushort_t u2 = xb[c2.x * 32 + j];
        ushort_t u3 = xb[c3.x * 32 + j];
        ushort_t u4 = xb[c4.x * 32 + j];
        ushort_t u5 = xb[c5.x * 32 + j];
        ushort_t u6 = xb[c6.x * 32 + j];
        ushort_t u7 = xb[c7.x * 32 + j];
        a0 += __int_as_float(c0.y) * bf16_to_f32(u0);
        a1 += __int_as_float(c1.y) * bf16_to_f32(u1);
        a2 += __int_as_float(c2.y) * bf16_to_f32(u2);
        a3 += __int_as_float(c3.y) * bf16_to_f32(u3);
        a0 += __int_as_float(c4.y) * bf16_to_f32(u4);
        a1 += __int_as_float(c5.y) * bf16_to_f32(u5);
        a2 += __int_as_float(c6.y) * bf16_to_f32(u6);
        a3 += __int_as_float(c7.y) * bf16_to_f32(u7);
    }
    for (; p + 6 < e; p += 8) {
        int2 c0 = ep[p];
        int2 c1 = ep[p + 2];
        int2 c2 = ep[p + 4];
        int2 c3 = ep[p + 6];
        ushort_t u0 = xb[c0.x * 32 + j];
        ushort_t u1 = xb[c1.x * 32 + j];
        ushort_t u2 = xb[c2.x * 32 + j];
        ushort_t u3 = xb[c3.x * 32 + j];
        a0 += __int_as_float(c0.y) * bf16_to_f32(u0);
        a1 += __int_as_float(c1.y) * bf16_to_f32(u1);
        a2 += __int_as_float(c2.y) * bf16_to_f32(u2);
        a3 += __int_as_float(c3.y) * bf16_to_f32(u3);
    }
    for (; p < e; p += 2) {
        int2 cv = ep[p];
        a0 += __int_as_float(cv.y) * bf16_to_f32(xb[cv.x * 32 + j]);
    }
    float acc = (a0 + a1) + (a2 + a3);
    acc += __shfl_xor(acc, 32, 64);
    if (half == 0) {
        if constexpr (OUT_BF16) {
            ((ushort_t*)outv)[r * 32 + j] = f32_to_bf16_rne(acc);
        } else {
            ((float*)outv)[r * 32 + j] = acc;
        }
    }
}

// ---------------- fallback path (fp32 throughout) ----------------
__global__ void spmm32_atomic_kernel(const int* __restrict__ row,
                                     const int* __restrict__ col,
                                     const float* __restrict__ val,
                                     const float* __restrict__ x,
                                     float* __restrict__ out) {
    int id = blockIdx.x * blockDim.x + threadIdx.x;
    int e = id >> 5;
    int j = id & 31;
    if (e >= N_EDGES) return;
    atomicAdd(&out[row[e] * 32 + j], val[e] * x[col[e] * 32 + j]);
}

__global__ void gemm_out_fallback_kernel(const float* __restrict__ g2,
                                         const float* __restrict__ W12,
                                         float* __restrict__ out) {
    int id = blockIdx.x * blockDim.x + threadIdx.x;
    int i = id >> 7;
    int j = id & 127;
    const float* g = g2 + i * 32;
    float acc = 0.f;
#pragma unroll
    for (int k = 0; k < 32; ++k) acc += g[k] * W12[k * 128 + j];
    out[id] = acc;
}

extern "C" void kernel_launch(void* const* d_in, const int* in_sizes, int n_in,
                              void* d_out, int out_size, void* d_ws, size_t ws_size,
                              hipStream_t stream) {
    const float* feat = (const float*)d_in[0];   // [N, 32]
    const float* W1   = (const float*)d_in[1];   // [32, 64]
    const float* W2   = (const float*)d_in[2];   // [64, 128]
    const int*   erow = (const int*)d_in[3];     // [E]
    const int*   ecol = (const int*)d_in[4];     // [E]
    const float* eval_= (const float*)d_in[5];   // [E]
    float* out = (float*)d_out;                  // [N, 128]

    // ws: W12[4096 f32] | xb[N*32 bf16] | g1b[N*32 bf16] | g2[N*32 f32] |
    //     ep[E int2] | cnt[NB] | offs[NB+1] | cur_b[NB] | rs[N+2]
    float*    W12   = (float*)d_ws;
    ushort_t* xb    = (ushort_t*)(W12 + 4096);
    ushort_t* g1b   = xb + (size_t)N_NODES * 32;
    float*    g2    = (float*)(g1b + (size_t)N_NODES * 32);
    int2*     ep    = (int2*)(g2 + (size_t)N_NODES * 32);
    int*      cnt   = (int*)(ep + N_EDGES);
    int*      offs  = cnt + NB;
    int*      cur_b = offs + NB + 1;
    int*      rs    = cur_b + NB;
    size_t    needed = (size_t)((char*)(rs + N_NODES + 2) - (char*)d_ws);

    // bucket-grouped intermediate lives in d_out (25.6MB <= 51.2MB), fully
    // consumed by rowsort before gemm_out overwrites d_out.
    int2* ebuf = (int2*)d_out;

    gemm_w12_kernel<<<16, 256, 0, stream>>>(W1, W2, W12);

    if (ws_size >= needed) {
        cvt_bf16_kernel<<<(N_NODES * 32 + 255) / 256, 256, 0, stream>>>(feat, xb);

        hipMemsetAsync(cnt, 0, NB * sizeof(int), stream);
        hist_bucket_kernel<<<256, 1024, 0, stream>>>(erow, cnt);
        scan_bucket_kernel<<<1, 1024, 0, stream>>>(cnt, offs, cur_b);
        scatter_bucket_kernel<<<256, 1024, 0, stream>>>(erow, ecol, eval_, cur_b, ebuf);
        rowsort_kernel<<<NB, 512, 0, stream>>>(offs, ebuf, ep, rs);

        spmm_csr_kernel<true><<<(N_NODES * 64) / 256, 256, 0, stream>>>(rs, ep, xb, g1b);
        spmm_csr_kernel<false><<<(N_NODES * 64) / 256, 256, 0, stream>>>(rs, ep, g1b, g2);

        gemm_out_kernel<<<1024, 256, 0, stream>>>(g2, W12, out);
    } else {
        // fallback: fp32 atomic path; reuse ws front as g1/g2
        float* g1f = (float*)d_ws + 4096;
        float* g2f = g1f + (size_t)N_NODES * 32;
        hipMemsetAsync(g1f, 0, (size_t)N_NODES * 32 * 2 * sizeof(float), stream);
        spmm32_atomic_kernel<<<(N_EDGES * 32) / 256, 256, 0, stream>>>(erow, ecol, eval_, feat, g1f);
        spmm32_atomic_kernel<<<(N_EDGES * 32) / 256, 256, 0, stream>>>(erow, ecol, eval_, g1f, g2f);
        gemm_out_fallback_kernel<<<(N_NODES * 128) / 256, 256, 0, stream>>>(g2f, W12, out);
    }
}